// Round 1
// baseline (3981.934 us; speedup 1.0000x reference)
//
#include <hip/hip_runtime.h>

// Problem: T=128, B=64, STATE=32, LATENT=16, AC=8, MS=8, SE=64, AE=16, H=64, OUT=18
// d_out layout: [0] = kl_loss, [1 .. 8192] = recon_loss[s*64+b]  (out_size = 8193, f32)
// d_ws layout:  [0, 6291456)  xi  (T,B,192) f32   = embed@Wi + bi
//               [6291456, 8388608) hid0 (T,B,64) f32
//               [8388608, +4) work-steal counter

#define XI_OFF   0
#define HID_OFF  6291456
#define CTR_OFF  8388608

// ---------------- KL kernel ----------------
__global__ __launch_bounds__(256) void kl_kernel(
    const float* __restrict__ lm, const float* __restrict__ lv,
    const float* __restrict__ lmt, const float* __restrict__ lvt,
    float* __restrict__ out) {
  __shared__ float ps[4];
  int idx = blockIdx.x * 256 + threadIdx.x;   // [0, 128*64*32)
  int g = idx & 31;
  int pair = idx >> 5;                        // t*64 + b
  const float* M = (g < 16) ? lm : lmt;
  const float* V = (g < 16) ? lv : lvt;
  int gg = g & 15;
  int cur = pair * 16 + gg;
  float mu = M[cur], lE = V[cur];
  float m = 0.f, lS = 0.f;
  if (pair >= 64) { m = M[cur - 1024]; lS = V[cur - 1024]; }  // previous t, same b
  float d = m - mu;
  float term = 0.5f * (lS - lE - 1.f + __expf(lE - lS) + d * d * __expf(-lS));
  #pragma unroll
  for (int off = 32; off; off >>= 1) term += __shfl_xor(term, off);
  if ((threadIdx.x & 63) == 0) ps[threadIdx.x >> 6] = term;
  __syncthreads();
  if (threadIdx.x == 0) atomicAdd(out, ps[0] + ps[1] + ps[2] + ps[3]);
}

// ---------------- Precompute: se, ae, embed, hidden, xi ----------------
__global__ __launch_bounds__(256, 2) void precompute_kernel(
    const float* __restrict__ state, const float* __restrict__ ac, const float* __restrict__ ms,
    const float* __restrict__ Wst, const float* __restrict__ bst,
    const float* __restrict__ Wac, const float* __restrict__ bac,
    const float* __restrict__ Wem, const float* __restrict__ bem,
    const float* __restrict__ Whd, const float* __restrict__ bhd,
    const float* __restrict__ Wi,  const float* __restrict__ bi,
    float* __restrict__ xi, float* __restrict__ hid0) {
  __shared__ float sWst[32 * 64];
  __shared__ float sWem[80 * 64];
  __shared__ float sWhd[24 * 64];
  __shared__ float sWac[8 * 16];
  __shared__ float sb[208];          // [0:64) b_state, [64:80) b_ac, [80:144) b_embed, [144:208) b_hid
  __shared__ float sin_[4][48];      // per-wave: state(32) | ac(8) | ms(8)
  __shared__ float sse[4][80];       // per-wave: se(64) | ae(16)
  __shared__ float semb[4][64];
  int tid = threadIdx.x, lane = tid & 63, w = tid >> 6;
  float wi0[64], wi1[64], wi2[64];   // Wi columns lane, 64+lane, 128+lane
  #pragma unroll
  for (int k = 0; k < 64; ++k) {
    wi0[k] = Wi[k * 192 + lane];
    wi1[k] = Wi[k * 192 + 64 + lane];
    wi2[k] = Wi[k * 192 + 128 + lane];
  }
  for (int i = tid; i < 32 * 64; i += 256) sWst[i] = Wst[i];
  for (int i = tid; i < 80 * 64; i += 256) sWem[i] = Wem[i];
  for (int i = tid; i < 24 * 64; i += 256) sWhd[i] = Whd[i];
  for (int i = tid; i < 8 * 16; i += 256) sWac[i] = Wac[i];
  if (tid < 64) sb[tid] = bst[tid];
  if (tid < 16) sb[64 + tid] = bac[tid];
  if (tid < 64) sb[80 + tid] = bem[tid];
  if (tid < 64) sb[144 + tid] = bhd[tid];
  float bi0 = bi[lane], bi1 = bi[64 + lane], bi2 = bi[128 + lane];
  __syncthreads();
  for (int cnt = 0; cnt < 4; ++cnt) {
    int pair = blockIdx.x * 16 + w * 4 + cnt;   // t*64 + b, in [0, 8192)
    if (lane < 32)      sin_[w][lane] = state[pair * 32 + lane];
    else if (lane < 40) sin_[w][lane] = ac[pair * 8 + (lane - 32)];
    else if (lane < 48) sin_[w][lane] = ms[pair * 8 + (lane - 40)];
    __syncthreads();
    float se = sb[lane];
    #pragma unroll
    for (int k = 0; k < 32; ++k) se += sin_[w][k] * sWst[k * 64 + lane];
    se = fmaxf(se, 0.f);
    float ae = 0.f;
    if (lane < 16) {
      ae = sb[64 + lane];
      #pragma unroll
      for (int k = 0; k < 8; ++k) ae += sin_[w][32 + k] * sWac[k * 16 + lane];
      ae = fmaxf(ae, 0.f);
    }
    __syncthreads();
    sse[w][lane] = se;
    if (lane < 16) sse[w][64 + lane] = ae;
    __syncthreads();
    float em = sb[80 + lane];
    #pragma unroll
    for (int k = 0; k < 80; ++k) em += sse[w][k] * sWem[k * 64 + lane];
    float hd = sb[144 + lane];
    #pragma unroll
    for (int k = 0; k < 16; ++k) hd += sse[w][64 + k] * sWhd[k * 64 + lane];
    #pragma unroll
    for (int k = 0; k < 8; ++k) hd += sin_[w][40 + k] * sWhd[(16 + k) * 64 + lane];
    hid0[pair * 64 + lane] = hd;
    semb[w][lane] = em;
    __syncthreads();
    float x0 = bi0, x1 = bi1, x2 = bi2;
    #pragma unroll
    for (int k = 0; k < 64; ++k) {
      float e = semb[w][k];
      x0 += e * wi0[k]; x1 += e * wi1[k]; x2 += e * wi2[k];
    }
    float* xo = xi + pair * 192;
    xo[lane] = x0; xo[64 + lane] = x1; xo[128 + lane] = x2;
    __syncthreads();
  }
}

// ---------------- Rollout: one wave per (t,b) sequence, work-stealing ----------------
__global__ __launch_bounds__(64, 2) void rollout_kernel(
    const float* __restrict__ xi, const float* __restrict__ hid0,
    const float* __restrict__ dones, const int* __restrict__ actions,
    const float* __restrict__ Whrz, const float* __restrict__ Whn,
    const float* __restrict__ bhn, const float* __restrict__ Wout,
    const float* __restrict__ bout, float* __restrict__ out,
    unsigned int* __restrict__ ctr) {
  __shared__ float sWoT[18 * 65];   // W_out transposed [j][k], stride 65 to spread banks
  __shared__ float sbo[18];
  int lane = threadIdx.x;
  float Wr[64], Wz[64], Wn[64];     // recurrent weight columns for this lane's hidden dim
  #pragma unroll
  for (int k = 0; k < 64; ++k) {
    Wr[k] = Whrz[k * 128 + lane];
    Wz[k] = Whrz[k * 128 + 64 + lane];
    Wn[k] = Whn[k * 64 + lane];
  }
  for (int i = lane; i < 18 * 64; i += 64) {
    int j = i >> 6, k = i & 63;
    sWoT[j * 65 + k] = Wout[k * 18 + j];
  }
  if (lane < 18) sbo[lane] = bout[lane];
  float bhn_r = bhn[lane];
  __syncthreads();
  int row = (lane < 18) ? lane : 0;
  while (true) {
    int seq = 0;
    if (lane == 0) seq = (int)atomicAdd(ctr, 1u);
    seq = __shfl(seq, 0);
    if (seq >= 128 * 64) break;
    int t = seq >> 6, b = seq & 63;       // t-ascending = longest-first (LPT scheduling)
    float h = hid0[(t * 64 + b) * 64 + lane];
    int u = t;
    for (int s = 0;; ++s, ++u) {
      float dflag = dones[u * 64 + b];
      if (dflag > 0.f) h = hid0[(u * 64 + b) * 64 + lane];   // episode reset
      const float* xb = xi + (u * 64 + b) * 192;
      float ar = xb[lane], az = xb[64 + lane];
      float an = 0.f;
      #pragma unroll
      for (int k = 0; k < 64; ++k) {
        float hk = __shfl(h, k);
        ar += hk * Wr[k];
        az += hk * Wz[k];
        an += hk * Wn[k];
      }
      float r = 1.f / (1.f + __expf(-ar));
      float z = 1.f / (1.f + __expf(-az));
      float pre = xb[128 + lane] + r * (an + bhn_r);
      float n = 1.f - 2.f / (1.f + __expf(2.f * pre));       // tanh
      h = (1.f - z) * n + z * h;
      // logits = h @ W_out + b_out  (18 outputs on lanes 0..17)
      float acc = (lane < 18) ? sbo[lane] : 0.f;
      #pragma unroll
      for (int k = 0; k < 64; ++k) {
        float hk = __shfl(h, k);
        acc += hk * sWoT[row * 65 + k];
      }
      float logit = (lane < 18) ? acc : -3.0e38f;
      float mx = logit;
      #pragma unroll
      for (int off = 32; off; off >>= 1) mx = fmaxf(mx, __shfl_xor(mx, off));
      float e = (lane < 18) ? __expf(logit - mx) : 0.f;
      #pragma unroll
      for (int off = 32; off; off >>= 1) e += __shfl_xor(e, off);
      float lse = mx + __logf(e);
      int a = actions[u * 64 + b];
      float la = __shfl(logit, a);
      if (lane == 0) atomicAdd(&out[1 + s * 64 + b], lse - la);
      if (dflag > 0.f || u == 127) break;   // mask is 0 for all later steps
    }
  }
}

extern "C" void kernel_launch(void* const* d_in, const int* in_sizes, int n_in,
                              void* d_out, int out_size, void* d_ws, size_t ws_size,
                              hipStream_t stream) {
  const float* state = (const float*)d_in[0];
  const float* lm    = (const float*)d_in[1];
  const float* lv    = (const float*)d_in[2];
  const float* lmt   = (const float*)d_in[3];
  const float* lvt   = (const float*)d_in[4];
  const float* ac    = (const float*)d_in[5];
  const float* ms    = (const float*)d_in[6];
  const int*   actions = (const int*)d_in[7];
  const float* dones = (const float*)d_in[8];
  const float* Wst = (const float*)d_in[9],  *bst = (const float*)d_in[10];
  const float* Wac = (const float*)d_in[11], *bac = (const float*)d_in[12];
  const float* Wem = (const float*)d_in[13], *bem = (const float*)d_in[14];
  const float* Whd = (const float*)d_in[15], *bhd = (const float*)d_in[16];
  const float* Wi  = (const float*)d_in[17], *bi  = (const float*)d_in[18];
  const float* Whrz = (const float*)d_in[19];
  const float* Whn  = (const float*)d_in[20], *bhn = (const float*)d_in[21];
  const float* Wout = (const float*)d_in[22], *bout = (const float*)d_in[23];
  float* out = (float*)d_out;
  float* xi   = (float*)((char*)d_ws + XI_OFF);
  float* hid0 = (float*)((char*)d_ws + HID_OFF);
  unsigned int* ctr = (unsigned int*)((char*)d_ws + CTR_OFF);

  hipMemsetAsync(d_out, 0, (size_t)out_size * sizeof(float), stream);
  hipMemsetAsync(ctr, 0, sizeof(unsigned int), stream);

  hipLaunchKernelGGL(kl_kernel, dim3(1024), dim3(256), 0, stream, lm, lv, lmt, lvt, out);
  hipLaunchKernelGGL(precompute_kernel, dim3(512), dim3(256), 0, stream,
                     state, ac, ms, Wst, bst, Wac, bac, Wem, bem, Whd, bhd, Wi, bi, xi, hid0);
  hipLaunchKernelGGL(rollout_kernel, dim3(2048), dim3(64), 0, stream,
                     xi, hid0, dones, actions, Whrz, Whn, bhn, Wout, bout, out, ctr);
}

// Round 2
// 437.398 us; speedup vs baseline: 9.1037x; 9.1037x over previous
//
#include <hip/hip_runtime.h>

// Problem: T=128, B=64, STATE=32, LATENT=16, AC=8, MS=8, SE=64, AE=16, H=64, OUT=18
// d_out layout: [0] = kl_loss, [1 .. 8192] = recon_loss[s*64+b]  (out_size = 8193, f32)
// d_ws layout:  [0, 6291456)  xi  (T,B,192) f32   = embed@Wi + bi
//               [6291456, 8388608) hid0 (T,B,64) f32
//               [8388608, +4) work-steal counter

#define XI_OFF   0
#define HID_OFF  6291456
#define CTR_OFF  8388608

typedef float f32x16 __attribute__((ext_vector_type(16)));

// ---------------- KL kernel ----------------
__global__ __launch_bounds__(256) void kl_kernel(
    const float* __restrict__ lm, const float* __restrict__ lv,
    const float* __restrict__ lmt, const float* __restrict__ lvt,
    float* __restrict__ out) {
  __shared__ float ps[4];
  int idx = blockIdx.x * 256 + threadIdx.x;   // [0, 128*64*32)
  int g = idx & 31;
  int pair = idx >> 5;                        // t*64 + b
  const float* M = (g < 16) ? lm : lmt;
  const float* V = (g < 16) ? lv : lvt;
  int gg = g & 15;
  int cur = pair * 16 + gg;
  float mu = M[cur], lE = V[cur];
  float m = 0.f, lS = 0.f;
  if (pair >= 64) { m = M[cur - 1024]; lS = V[cur - 1024]; }  // previous t, same b
  float d = m - mu;
  float term = 0.5f * (lS - lE - 1.f + __expf(lE - lS) + d * d * __expf(-lS));
  #pragma unroll
  for (int off = 32; off; off >>= 1) term += __shfl_xor(term, off);
  if ((threadIdx.x & 63) == 0) ps[threadIdx.x >> 6] = term;
  __syncthreads();
  if (threadIdx.x == 0) atomicAdd(out, ps[0] + ps[1] + ps[2] + ps[3]);
}

// ---------------- Precompute: se, ae, embed, hidden, xi ----------------
__global__ __launch_bounds__(256, 2) void precompute_kernel(
    const float* __restrict__ state, const float* __restrict__ ac, const float* __restrict__ ms,
    const float* __restrict__ Wst, const float* __restrict__ bst,
    const float* __restrict__ Wac, const float* __restrict__ bac,
    const float* __restrict__ Wem, const float* __restrict__ bem,
    const float* __restrict__ Whd, const float* __restrict__ bhd,
    const float* __restrict__ Wi,  const float* __restrict__ bi,
    float* __restrict__ xi, float* __restrict__ hid0) {
  __shared__ float sWst[32 * 64];
  __shared__ float sWem[80 * 64];
  __shared__ float sWhd[24 * 64];
  __shared__ float sWac[8 * 16];
  __shared__ float sb[208];          // [0:64) b_state, [64:80) b_ac, [80:144) b_embed, [144:208) b_hid
  __shared__ float sin_[4][48];      // per-wave: state(32) | ac(8) | ms(8)
  __shared__ float sse[4][80];       // per-wave: se(64) | ae(16)
  __shared__ float semb[4][64];
  int tid = threadIdx.x, lane = tid & 63, w = tid >> 6;
  f32x16 wi0[4], wi1[4], wi2[4];     // Wi columns lane, 64+lane, 128+lane (SSA vectors: stay in VGPRs)
  #pragma unroll
  for (int k = 0; k < 64; ++k) {
    wi0[k >> 4][k & 15] = Wi[k * 192 + lane];
    wi1[k >> 4][k & 15] = Wi[k * 192 + 64 + lane];
    wi2[k >> 4][k & 15] = Wi[k * 192 + 128 + lane];
  }
  for (int i = tid; i < 32 * 64; i += 256) sWst[i] = Wst[i];
  for (int i = tid; i < 80 * 64; i += 256) sWem[i] = Wem[i];
  for (int i = tid; i < 24 * 64; i += 256) sWhd[i] = Whd[i];
  for (int i = tid; i < 8 * 16; i += 256) sWac[i] = Wac[i];
  if (tid < 64) sb[tid] = bst[tid];
  if (tid < 16) sb[64 + tid] = bac[tid];
  if (tid < 64) sb[80 + tid] = bem[tid];
  if (tid < 64) sb[144 + tid] = bhd[tid];
  float bi0 = bi[lane], bi1 = bi[64 + lane], bi2 = bi[128 + lane];
  __syncthreads();
  for (int cnt = 0; cnt < 4; ++cnt) {
    int pair = blockIdx.x * 16 + w * 4 + cnt;   // t*64 + b, in [0, 8192)
    if (lane < 32)      sin_[w][lane] = state[pair * 32 + lane];
    else if (lane < 40) sin_[w][lane] = ac[pair * 8 + (lane - 32)];
    else if (lane < 48) sin_[w][lane] = ms[pair * 8 + (lane - 40)];
    __syncthreads();
    float se = sb[lane];
    #pragma unroll
    for (int k = 0; k < 32; ++k) se += sin_[w][k] * sWst[k * 64 + lane];
    se = fmaxf(se, 0.f);
    float ae = 0.f;
    if (lane < 16) {
      ae = sb[64 + lane];
      #pragma unroll
      for (int k = 0; k < 8; ++k) ae += sin_[w][32 + k] * sWac[k * 16 + lane];
      ae = fmaxf(ae, 0.f);
    }
    __syncthreads();
    sse[w][lane] = se;
    if (lane < 16) sse[w][64 + lane] = ae;
    __syncthreads();
    float em = sb[80 + lane];
    #pragma unroll
    for (int k = 0; k < 80; ++k) em += sse[w][k] * sWem[k * 64 + lane];
    float hd = sb[144 + lane];
    #pragma unroll
    for (int k = 0; k < 16; ++k) hd += sse[w][64 + k] * sWhd[k * 64 + lane];
    #pragma unroll
    for (int k = 0; k < 8; ++k) hd += sin_[w][40 + k] * sWhd[(16 + k) * 64 + lane];
    hid0[pair * 64 + lane] = hd;
    semb[w][lane] = em;
    __syncthreads();
    float x0 = bi0, x1 = bi1, x2 = bi2;
    #pragma unroll
    for (int k = 0; k < 64; ++k) {
      float e = semb[w][k];
      x0 += e * wi0[k >> 4][k & 15];
      x1 += e * wi1[k >> 4][k & 15];
      x2 += e * wi2[k >> 4][k & 15];
    }
    float* xo = xi + pair * 192;
    xo[lane] = x0; xo[64 + lane] = x1; xo[128 + lane] = x2;
    __syncthreads();
  }
}

// ---------------- Rollout: one wave per (t,b) sequence, work-stealing ----------------
// Weights register-resident as ext_vector SSA values; h broadcast via LDS float4 reads;
// all per-step global reads software-pipelined one step ahead.
__global__ __launch_bounds__(64, 2) void rollout_kernel(
    const float* __restrict__ xi, const float* __restrict__ hid0,
    const float* __restrict__ dones, const int* __restrict__ actions,
    const float* __restrict__ Whrz, const float* __restrict__ Whn,
    const float* __restrict__ bhn, const float* __restrict__ Wout,
    const float* __restrict__ bout, float* __restrict__ out,
    unsigned int* __restrict__ ctr) {
  __shared__ __attribute__((aligned(16))) float sWoT[18 * 68];  // stride 68: 16B-aligned rows
  __shared__ __attribute__((aligned(16))) float sh[64];
  __shared__ float sbo[18];
  int lane = threadIdx.x;
  f32x16 Wr[4], Wz[4], Wn[4];   // recurrent weight columns for this lane's hidden dim
  #pragma unroll
  for (int k = 0; k < 64; ++k) {
    Wr[k >> 4][k & 15] = Whrz[k * 128 + lane];
    Wz[k >> 4][k & 15] = Whrz[k * 128 + 64 + lane];
    Wn[k >> 4][k & 15] = Whn[k * 64 + lane];
  }
  for (int i = lane; i < 18 * 64; i += 64) {
    int j = i >> 6, k = i & 63;
    sWoT[j * 68 + k] = Wout[k * 18 + j];          // transposed: [j][k]
  }
  if (lane < 18) sbo[lane] = bout[lane];
  float bhn_r = bhn[lane];
  __syncthreads();
  int row = (lane < 18) ? lane : 0;
  while (true) {
    int seq = 0;
    if (lane == 0) seq = (int)atomicAdd(ctr, 1u);
    seq = __shfl(seq, 0);
    if (seq >= 128 * 64) break;
    int t = seq >> 6, b = seq & 63;       // t-ascending = longest-first (LPT scheduling)
    int u = t;
    float h = hid0[(t * 64 + b) * 64 + lane];     // covers the s=0 reset case too
    const float* xb = xi + (t * 64 + b) * 192;
    float x0 = xb[lane], x1 = xb[64 + lane], x2 = xb[128 + lane];
    float d = dones[t * 64 + b];
    int  act = actions[t * 64 + b];
    for (int s = 0;; ++s) {
      int un = (u < 127) ? u + 1 : 127;
      // -------- prefetch next step (latency hidden under compute) --------
      const float* xn = xi + (un * 64 + b) * 192;
      float nx0 = xn[lane], nx1 = xn[64 + lane], nx2 = xn[128 + lane];
      float nd = dones[un * 64 + b];
      int   na = actions[un * 64 + b];
      float nh = hid0[(un * 64 + b) * 64 + lane];
      // -------- GRU gates: ar/az/an = h_old @ {Wr,Wz,Wn} --------
      sh[lane] = h;                     // wave-synchronous LDS broadcast (single wave/block)
      float ar = x0, az = x1, an = 0.f;
      #pragma unroll
      for (int q = 0; q < 16; ++q) {
        float4 h4 = *(const float4*)&sh[q * 4];   // same addr all lanes: broadcast
        #pragma unroll
        for (int j = 0; j < 4; ++j) {
          int k = q * 4 + j;
          float hk = (&h4.x)[j];
          ar += hk * Wr[k >> 4][k & 15];
          az += hk * Wz[k >> 4][k & 15];
          an += hk * Wn[k >> 4][k & 15];
        }
      }
      float r = 1.f / (1.f + __expf(-ar));
      float z = 1.f / (1.f + __expf(-az));
      float pre = x2 + r * (an + bhn_r);
      float n = 1.f - 2.f / (1.f + __expf(2.f * pre));       // tanh
      h = (1.f - z) * n + z * h;
      // -------- logits = h_new @ W_out + b_out (lanes 0..17) --------
      sh[lane] = h;                     // broadcast h_new (same-wave order guarantees WAR)
      float acc = sbo[row];
      #pragma unroll
      for (int q = 0; q < 16; ++q) {
        float4 h4 = *(const float4*)&sh[q * 4];
        float4 w4 = *(const float4*)&sWoT[row * 68 + q * 4];
        acc += h4.x * w4.x + h4.y * w4.y + h4.z * w4.z + h4.w * w4.w;
      }
      float logit = (lane < 18) ? acc : -3.0e38f;
      float mx = logit;
      #pragma unroll
      for (int off = 32; off; off >>= 1) mx = fmaxf(mx, __shfl_xor(mx, off));
      float e = (lane < 18) ? __expf(logit - mx) : 0.f;
      #pragma unroll
      for (int off = 32; off; off >>= 1) e += __shfl_xor(e, off);
      float lse = mx + __logf(e);
      float la = __shfl(logit, act);
      if (lane == 0) atomicAdd(&out[1 + s * 64 + b], lse - la);
      if (d > 0.f || u == 127) break;   // episode mask is 0 for all later steps
      // -------- advance --------
      u = un; x0 = nx0; x1 = nx1; x2 = nx2; d = nd; act = na;
      if (nd > 0.f) h = nh;             // reset at next step start (hid0[u_next])
    }
  }
}

extern "C" void kernel_launch(void* const* d_in, const int* in_sizes, int n_in,
                              void* d_out, int out_size, void* d_ws, size_t ws_size,
                              hipStream_t stream) {
  const float* state = (const float*)d_in[0];
  const float* lm    = (const float*)d_in[1];
  const float* lv    = (const float*)d_in[2];
  const float* lmt   = (const float*)d_in[3];
  const float* lvt   = (const float*)d_in[4];
  const float* ac    = (const float*)d_in[5];
  const float* ms    = (const float*)d_in[6];
  const int*   actions = (const int*)d_in[7];
  const float* dones = (const float*)d_in[8];
  const float* Wst = (const float*)d_in[9],  *bst = (const float*)d_in[10];
  const float* Wac = (const float*)d_in[11], *bac = (const float*)d_in[12];
  const float* Wem = (const float*)d_in[13], *bem = (const float*)d_in[14];
  const float* Whd = (const float*)d_in[15], *bhd = (const float*)d_in[16];
  const float* Wi  = (const float*)d_in[17], *bi  = (const float*)d_in[18];
  const float* Whrz = (const float*)d_in[19];
  const float* Whn  = (const float*)d_in[20], *bhn = (const float*)d_in[21];
  const float* Wout = (const float*)d_in[22], *bout = (const float*)d_in[23];
  float* out = (float*)d_out;
  float* xi   = (float*)((char*)d_ws + XI_OFF);
  float* hid0 = (float*)((char*)d_ws + HID_OFF);
  unsigned int* ctr = (unsigned int*)((char*)d_ws + CTR_OFF);

  hipMemsetAsync(d_out, 0, (size_t)out_size * sizeof(float), stream);
  hipMemsetAsync(ctr, 0, sizeof(unsigned int), stream);

  hipLaunchKernelGGL(kl_kernel, dim3(1024), dim3(256), 0, stream, lm, lv, lmt, lvt, out);
  hipLaunchKernelGGL(precompute_kernel, dim3(512), dim3(256), 0, stream,
                     state, ac, ms, Wst, bst, Wac, bac, Wem, bem, Whd, bhd, Wi, bi, xi, hid0);
  hipLaunchKernelGGL(rollout_kernel, dim3(2048), dim3(64), 0, stream,
                     xi, hid0, dones, actions, Whrz, Whn, bhn, Wout, bout, out, ctr);
}

// Round 3
// 285.054 us; speedup vs baseline: 13.9691x; 1.5344x over previous
//
#include <hip/hip_runtime.h>

// Problem: T=128, B=64, STATE=32, LATENT=16, AC=8, MS=8, SE=64, AE=16, H=64, OUT=18
// d_out layout: [0] = kl_loss, [1 .. 8192] = recon_loss[s*64+b]  (out_size = 8193, f32)
// d_ws layout:  [0, 6291456)  xi  (T,B,192) f32   = embed@Wi + bi
//               [6291456, 8388608) hid0 (T,B,64) f32
//               [8388608, +4) work-steal counter

#define XI_OFF   0
#define HID_OFF  6291456
#define CTR_OFF  8388608

typedef float f32x2  __attribute__((ext_vector_type(2)));
typedef float f32x16 __attribute__((ext_vector_type(16)));

// ---------------- KL kernel ----------------
__global__ __launch_bounds__(256) void kl_kernel(
    const float* __restrict__ lm, const float* __restrict__ lv,
    const float* __restrict__ lmt, const float* __restrict__ lvt,
    float* __restrict__ out) {
  __shared__ float ps[4];
  int idx = blockIdx.x * 256 + threadIdx.x;   // [0, 128*64*32)
  int g = idx & 31;
  int pair = idx >> 5;                        // t*64 + b
  const float* M = (g < 16) ? lm : lmt;
  const float* V = (g < 16) ? lv : lvt;
  int gg = g & 15;
  int cur = pair * 16 + gg;
  float mu = M[cur], lE = V[cur];
  float m = 0.f, lS = 0.f;
  if (pair >= 64) { m = M[cur - 1024]; lS = V[cur - 1024]; }  // previous t, same b
  float d = m - mu;
  float term = 0.5f * (lS - lE - 1.f + __expf(lE - lS) + d * d * __expf(-lS));
  #pragma unroll
  for (int off = 32; off; off >>= 1) term += __shfl_xor(term, off);
  if ((threadIdx.x & 63) == 0) ps[threadIdx.x >> 6] = term;
  __syncthreads();
  if (threadIdx.x == 0) atomicAdd(out, ps[0] + ps[1] + ps[2] + ps[3]);
}

// ---------------- Precompute: se, ae, embed, hidden, xi ----------------
// (256,1): up to 512 VGPRs/lane -> wi arrays stay in true registers, no spill.
__global__ __launch_bounds__(256, 1) void precompute_kernel(
    const float* __restrict__ state, const float* __restrict__ ac, const float* __restrict__ ms,
    const float* __restrict__ Wst, const float* __restrict__ bst,
    const float* __restrict__ Wac, const float* __restrict__ bac,
    const float* __restrict__ Wem, const float* __restrict__ bem,
    const float* __restrict__ Whd, const float* __restrict__ bhd,
    const float* __restrict__ Wi,  const float* __restrict__ bi,
    float* __restrict__ xi, float* __restrict__ hid0) {
  __shared__ float sWst[32 * 64];
  __shared__ float sWem[80 * 64];
  __shared__ float sWhd[24 * 64];
  __shared__ float sWac[8 * 16];
  __shared__ float sb[208];          // [0:64) b_state, [64:80) b_ac, [80:144) b_embed, [144:208) b_hid
  __shared__ float sin_[4][48];      // per-wave: state(32) | ac(8) | ms(8)
  __shared__ float sse[4][80];       // per-wave: se(64) | ae(16)
  __shared__ float semb[4][64];
  int tid = threadIdx.x, lane = tid & 63, w = tid >> 6;
  f32x16 wi0[4], wi1[4], wi2[4];     // Wi columns lane, 64+lane, 128+lane
  #pragma unroll
  for (int k = 0; k < 64; ++k) {
    wi0[k >> 4][k & 15] = Wi[k * 192 + lane];
    wi1[k >> 4][k & 15] = Wi[k * 192 + 64 + lane];
    wi2[k >> 4][k & 15] = Wi[k * 192 + 128 + lane];
  }
  for (int i = tid; i < 32 * 64; i += 256) sWst[i] = Wst[i];
  for (int i = tid; i < 80 * 64; i += 256) sWem[i] = Wem[i];
  for (int i = tid; i < 24 * 64; i += 256) sWhd[i] = Whd[i];
  for (int i = tid; i < 8 * 16; i += 256) sWac[i] = Wac[i];
  if (tid < 64) sb[tid] = bst[tid];
  if (tid < 16) sb[64 + tid] = bac[tid];
  if (tid < 64) sb[80 + tid] = bem[tid];
  if (tid < 64) sb[144 + tid] = bhd[tid];
  float bi0 = bi[lane], bi1 = bi[64 + lane], bi2 = bi[128 + lane];
  __syncthreads();
  for (int cnt = 0; cnt < 4; ++cnt) {
    int pair = blockIdx.x * 16 + w * 4 + cnt;   // t*64 + b, in [0, 8192)
    if (lane < 32)      sin_[w][lane] = state[pair * 32 + lane];
    else if (lane < 40) sin_[w][lane] = ac[pair * 8 + (lane - 32)];
    else if (lane < 48) sin_[w][lane] = ms[pair * 8 + (lane - 40)];
    __syncthreads();
    float se = sb[lane];
    #pragma unroll
    for (int k = 0; k < 32; ++k) se += sin_[w][k] * sWst[k * 64 + lane];
    se = fmaxf(se, 0.f);
    float ae = 0.f;
    if (lane < 16) {
      ae = sb[64 + lane];
      #pragma unroll
      for (int k = 0; k < 8; ++k) ae += sin_[w][32 + k] * sWac[k * 16 + lane];
      ae = fmaxf(ae, 0.f);
    }
    __syncthreads();
    sse[w][lane] = se;
    if (lane < 16) sse[w][64 + lane] = ae;
    __syncthreads();
    float em = sb[80 + lane];
    #pragma unroll
    for (int k = 0; k < 80; ++k) em += sse[w][k] * sWem[k * 64 + lane];
    float hd = sb[144 + lane];
    #pragma unroll
    for (int k = 0; k < 16; ++k) hd += sse[w][64 + k] * sWhd[k * 64 + lane];
    #pragma unroll
    for (int k = 0; k < 8; ++k) hd += sin_[w][40 + k] * sWhd[(16 + k) * 64 + lane];
    hid0[pair * 64 + lane] = hd;
    semb[w][lane] = em;
    __syncthreads();
    float x0 = bi0, x1 = bi1, x2 = bi2;
    #pragma unroll
    for (int k = 0; k < 64; ++k) {
      float e = semb[w][k];
      x0 += e * wi0[k >> 4][k & 15];
      x1 += e * wi1[k >> 4][k & 15];
      x2 += e * wi2[k >> 4][k & 15];
    }
    float* xo = xi + pair * 192;
    xo[lane] = x0; xo[64 + lane] = x1; xo[128 + lane] = x2;
    __syncthreads();
  }
}

// ---------------- Rollout: one wave per (t,b) sequence, work-stealing ----------------
// (64,1): 512-VGPR budget -> all weights in true arch VGPRs (no AGPR moves, no spill).
// Gates via v_pk_fma_f32 (f32x2). Softmax via LDS gather + in-register reduce.
__global__ __launch_bounds__(64, 1) void rollout_kernel(
    const float* __restrict__ xi, const float* __restrict__ hid0,
    const float* __restrict__ dones, const int* __restrict__ actions,
    const float* __restrict__ Whrz, const float* __restrict__ Whn,
    const float* __restrict__ bhn, const float* __restrict__ Wout,
    const float* __restrict__ bout, float* __restrict__ out,
    unsigned int* __restrict__ ctr) {
  __shared__ __attribute__((aligned(16))) float sWoT[18 * 68];  // [j][k], stride 68 (272B, 16B-mult)
  __shared__ __attribute__((aligned(16))) float sh[64];
  __shared__ __attribute__((aligned(16))) float slog[24];       // 18 logits + 2 sentinels + pad
  __shared__ float sbo[18];
  int lane = threadIdx.x;
  f32x2 Wr[32], Wz[32], Wn[32];   // recurrent weight columns, (even,odd) k-pairs
  #pragma unroll
  for (int k = 0; k < 32; ++k) {
    Wr[k] = f32x2{Whrz[(2 * k) * 128 + lane],      Whrz[(2 * k + 1) * 128 + lane]};
    Wz[k] = f32x2{Whrz[(2 * k) * 128 + 64 + lane], Whrz[(2 * k + 1) * 128 + 64 + lane]};
    Wn[k] = f32x2{Whn[(2 * k) * 64 + lane],        Whn[(2 * k + 1) * 64 + lane]};
  }
  for (int i = lane; i < 18 * 64; i += 64) {
    int j = i >> 6, k = i & 63;
    sWoT[j * 68 + k] = Wout[k * 18 + j];          // transposed: [j][k]
  }
  if (lane < 18) sbo[lane] = bout[lane];
  if (lane < 2)  slog[18 + lane] = -3.0e38f;      // sentinels, never overwritten
  float bhn_r = bhn[lane];
  __syncthreads();
  int row = (lane < 18) ? lane : 0;
  while (true) {
    int seq = 0;
    if (lane == 0) seq = (int)atomicAdd(ctr, 1u);
    seq = __shfl(seq, 0);
    if (seq >= 128 * 64) break;
    int t = seq >> 6, b = seq & 63;       // t-ascending = longest-first (LPT scheduling)
    int u = t;
    float h = hid0[(t * 64 + b) * 64 + lane];     // covers the s=0 reset case too
    const float* xb = xi + (t * 64 + b) * 192;
    float x0 = xb[lane], x1 = xb[64 + lane], x2 = xb[128 + lane];
    float d = dones[t * 64 + b];
    int  act = actions[t * 64 + b];
    for (int s = 0;; ++s) {
      int un = (u < 127) ? u + 1 : 127;
      // -------- prefetch next step (latency hidden under this step's compute) --------
      const float* xn = xi + (un * 64 + b) * 192;
      float nx0 = xn[lane], nx1 = xn[64 + lane], nx2 = xn[128 + lane];
      float nd = dones[un * 64 + b];
      int   na = actions[un * 64 + b];
      float nh = hid0[(un * 64 + b) * 64 + lane];
      // -------- GRU gates: h_old @ {Wr,Wz,Wn} via packed f32 FMA --------
      sh[lane] = h;                     // wave-synchronous LDS broadcast (1 wave/block)
      f32x2 ar2 = {0.f, 0.f}, az2 = {0.f, 0.f}, an2 = {0.f, 0.f};
      #pragma unroll
      for (int q = 0; q < 16; ++q) {
        float4 h4 = *(const float4*)&sh[q * 4];   // same addr all lanes: broadcast, no conflict
        f32x2 hA = {h4.x, h4.y}, hB = {h4.z, h4.w};
        ar2 += hA * Wr[2 * q]; ar2 += hB * Wr[2 * q + 1];
        az2 += hA * Wz[2 * q]; az2 += hB * Wz[2 * q + 1];
        an2 += hA * Wn[2 * q]; an2 += hB * Wn[2 * q + 1];
      }
      float ar = x0 + ar2.x + ar2.y;
      float az = x1 + az2.x + az2.y;
      float an = an2.x + an2.y;
      float r = 1.f / (1.f + __expf(-ar));
      float z = 1.f / (1.f + __expf(-az));
      float pre = x2 + r * (an + bhn_r);
      float n = 1.f - 2.f / (1.f + __expf(2.f * pre));       // tanh
      h = (1.f - z) * n + z * h;
      // -------- logits = h_new @ W_out + b_out (lanes 0..17; packed) --------
      sh[lane] = h;                     // per-wave DS ordering: prior reads already done
      f32x2 acc2 = {0.f, 0.f};
      #pragma unroll
      for (int q = 0; q < 16; ++q) {
        float4 h4 = *(const float4*)&sh[q * 4];
        float4 w4 = *(const float4*)&sWoT[row * 68 + q * 4];
        acc2 += f32x2{h4.x, h4.y} * f32x2{w4.x, w4.y};
        acc2 += f32x2{h4.z, h4.w} * f32x2{w4.z, w4.w};
      }
      float acc = sbo[row] + acc2.x + acc2.y;
      if (lane < 18) slog[lane] = acc;
      // -------- softmax: LDS gather, in-register reduce (no bpermute chain) --------
      float4 L0 = *(const float4*)&slog[0];
      float4 L1 = *(const float4*)&slog[4];
      float4 L2 = *(const float4*)&slog[8];
      float4 L3 = *(const float4*)&slog[12];
      float4 L4 = *(const float4*)&slog[16];     // includes 2 sentinels (-3e38 -> exp 0)
      float m0 = fmaxf(fmaxf(L0.x, L0.y), fmaxf(L0.z, L0.w));
      float m1 = fmaxf(fmaxf(L1.x, L1.y), fmaxf(L1.z, L1.w));
      float m2 = fmaxf(fmaxf(L2.x, L2.y), fmaxf(L2.z, L2.w));
      float m3 = fmaxf(fmaxf(L3.x, L3.y), fmaxf(L3.z, L3.w));
      float m4 = fmaxf(fmaxf(L4.x, L4.y), fmaxf(L4.z, L4.w));
      float mx = fmaxf(fmaxf(fmaxf(m0, m1), fmaxf(m2, m3)), m4);
      float s0 = __expf(L0.x - mx) + __expf(L0.y - mx) + __expf(L0.z - mx) + __expf(L0.w - mx);
      float s1 = __expf(L1.x - mx) + __expf(L1.y - mx) + __expf(L1.z - mx) + __expf(L1.w - mx);
      float s2 = __expf(L2.x - mx) + __expf(L2.y - mx) + __expf(L2.z - mx) + __expf(L2.w - mx);
      float s3 = __expf(L3.x - mx) + __expf(L3.y - mx) + __expf(L3.z - mx) + __expf(L3.w - mx);
      float s4 = __expf(L4.x - mx) + __expf(L4.y - mx) + __expf(L4.z - mx) + __expf(L4.w - mx);
      float ssum = (s0 + s1) + (s2 + s3) + s4;
      float la = slog[act];                      // uniform addr: broadcast read
      float lse = mx + __logf(ssum);
      if (lane == 0) atomicAdd(&out[1 + s * 64 + b], lse - la);
      if (d > 0.f || u == 127) break;   // episode mask is 0 for all later steps
      // -------- advance --------
      u = un; x0 = nx0; x1 = nx1; x2 = nx2; d = nd; act = na;
      if (nd > 0.f) h = nh;             // reset at next step start (hid0[u_next])
    }
  }
}

extern "C" void kernel_launch(void* const* d_in, const int* in_sizes, int n_in,
                              void* d_out, int out_size, void* d_ws, size_t ws_size,
                              hipStream_t stream) {
  const float* state = (const float*)d_in[0];
  const float* lm    = (const float*)d_in[1];
  const float* lv    = (const float*)d_in[2];
  const float* lmt   = (const float*)d_in[3];
  const float* lvt   = (const float*)d_in[4];
  const float* ac    = (const float*)d_in[5];
  const float* ms    = (const float*)d_in[6];
  const int*   actions = (const int*)d_in[7];
  const float* dones = (const float*)d_in[8];
  const float* Wst = (const float*)d_in[9],  *bst = (const float*)d_in[10];
  const float* Wac = (const float*)d_in[11], *bac = (const float*)d_in[12];
  const float* Wem = (const float*)d_in[13], *bem = (const float*)d_in[14];
  const float* Whd = (const float*)d_in[15], *bhd = (const float*)d_in[16];
  const float* Wi  = (const float*)d_in[17], *bi  = (const float*)d_in[18];
  const float* Whrz = (const float*)d_in[19];
  const float* Whn  = (const float*)d_in[20], *bhn = (const float*)d_in[21];
  const float* Wout = (const float*)d_in[22], *bout = (const float*)d_in[23];
  float* out = (float*)d_out;
  float* xi   = (float*)((char*)d_ws + XI_OFF);
  float* hid0 = (float*)((char*)d_ws + HID_OFF);
  unsigned int* ctr = (unsigned int*)((char*)d_ws + CTR_OFF);

  hipMemsetAsync(d_out, 0, (size_t)out_size * sizeof(float), stream);
  hipMemsetAsync(ctr, 0, sizeof(unsigned int), stream);

  hipLaunchKernelGGL(kl_kernel, dim3(1024), dim3(256), 0, stream, lm, lv, lmt, lvt, out);
  hipLaunchKernelGGL(precompute_kernel, dim3(512), dim3(256), 0, stream,
                     state, ac, ms, Wst, bst, Wac, bac, Wem, bem, Whd, bhd, Wi, bi, xi, hid0);
  hipLaunchKernelGGL(rollout_kernel, dim3(2048), dim3(64), 0, stream,
                     xi, hid0, dones, actions, Whrz, Whn, bhn, Wout, bout, out, ctr);
}